// Round 9
// baseline (321.284 us; speedup 1.0000x reference)
//
#include <hip/hip_runtime.h>
#include <math.h>

#define IMG  1024
#define TILE 64
#define HALO 12
#define SPP  52              // words/row: 2 pad + 44 data (words 2..45) + 6 pad (46..51)
#define NPRED (90*SPP)       // buffer rows 0..89 = px rows -1..88 (guard top/bottom)
#define SEN2 0x40004000u     // (2.0h,2.0h) sentinel = +inf (all real values <= 1)

// pred: fp16 pair-packed 2 px/word, single LDS buffer, in-place erode
// (read-all -> barrier -> write-all). targ: binary bit-packed 32 px/word.
typedef _Float16 h2 __attribute__((ext_vector_type(2)));
union UH { unsigned u; h2 h; };
__device__ __forceinline__ h2 u2h(unsigned u){ UH x; x.u=u; return x.h; }
__device__ __forceinline__ unsigned h2u(h2 h){ UH x; x.h=h; return x.u; }
__device__ __forceinline__ h2 pmin(h2 a, h2 b){ return __builtin_elementwise_min(a,b); }
__device__ __forceinline__ h2 pmax(h2 a, h2 b){ return __builtin_elementwise_max(a,b); }
__device__ __forceinline__ h2 funnel(h2 hi_src, h2 lo_src){
  return u2h((h2u(lo_src)>>16) | (h2u(hi_src)<<16));
}
__device__ __forceinline__ float sigmoidf(float x){ return 1.0f/(1.0f+__expf(-x)); }
__device__ __forceinline__ h2 unsent(h2 x, h2 onev, h2 zerov){
  h2 t = pmax(x-onev, zerov); return x - t - t;   // 2.0 -> 0, identity on [0,1]
}
__device__ __forceinline__ unsigned extract8(unsigned w0, unsigned w1, unsigned w2, int bp){
  unsigned long long lo = (unsigned long long)w0 | ((unsigned long long)w1<<32);
  unsigned long long hi = (unsigned long long)w1 | ((unsigned long long)w2<<32);
  unsigned a = (unsigned)(lo >> bp);
  unsigned b = (unsigned)(hi >> (bp & 31));
  return ((bp < 32) ? a : b) & 0xFFu;
}

template<bool BND>
__device__ void pipeline(const float* __restrict__ pred, const int* __restrict__ targ,
                         long base, int gr0, int gc0, int tid,
                         unsigned* P, unsigned* Ta,
                         h2 val[8], h2 skel[8], unsigned &tbits, unsigned &skbits) {
  // ---- stamp guard rows (px -1, 88) and pad cols {0,1,46..51} ----
  for (int i = tid; i < 104; i += 256) {
    int r = (i < 52) ? 0 : 89, c = (i < 52) ? i : i - 52;
    P[r*SPP + c] = SEN2;
  }
  for (int i = tid; i < 704; i += 256) {
    int r = 1 + (i >> 3), w = i & 7;
    w = (w < 2) ? w : 44 + w;
    P[r*SPP + w] = SEN2;
  }
  // ---- global -> LDS ----
  if (!BND) {
    #pragma unroll
    for (int k=0;k<4;++k){
      int u = tid + (k<<8);
      if (u < 968){                          // 88 rows x 11 groups of 8 px
        int r = u/11, q = u - r*11;
        long g = base + (long)(gr0+r)*IMG + gc0 + (q<<3);
        float4 pa = *(const float4*)(pred+g);
        float4 pb = *(const float4*)(pred+g+4);
        h2 w0 = {(_Float16)sigmoidf(pa.x), (_Float16)sigmoidf(pa.y)};
        h2 w1 = {(_Float16)sigmoidf(pa.z), (_Float16)sigmoidf(pa.w)};
        h2 w2 = {(_Float16)sigmoidf(pb.x), (_Float16)sigmoidf(pb.y)};
        h2 w3 = {(_Float16)sigmoidf(pb.z), (_Float16)sigmoidf(pb.w)};
        int o = (1+r)*SPP + 2 + (q<<2);
        uint2 d0; d0.x=h2u(w0); d0.y=h2u(w1);
        uint2 d1; d1.x=h2u(w2); d1.y=h2u(w3);
        *(uint2*)&P[o]   = d0;
        *(uint2*)&P[o+2] = d1;
      }
    }
    #pragma unroll
    for (int k=0;k<2;++k){
      int u = tid + (k<<8);
      if (u < 264){                          // 88 rows x 3 bit-words
        int r = u/3, w = u - r*3;
        long g = base + (long)(gr0+r)*IMG + gc0 + (w<<5);
        unsigned bits = 0;
        #pragma unroll
        for (int i=0;i<8;++i){
          if (w < 2 || i < 6) {
            int4 tv = *(const int4*)(targ + g + (i<<2));
            unsigned nib = (unsigned)(tv.x!=0) | ((unsigned)(tv.y!=0)<<1)
                         | ((unsigned)(tv.z!=0)<<2) | ((unsigned)(tv.w!=0)<<3);
            bits |= nib << (i<<2);
          }
        }
        if (w==2) bits |= 0xFF000000u;       // pseudo px 88..95: erode-neutral 1
        Ta[u] = bits;
      }
    }
  } else {
    for (int i=tid; i<88*44; i+=256){
      int r = i/44, wd = i - r*44;
      int gr = gr0 + r;
      bool rok = (unsigned)gr < (unsigned)IMG;
      int gca = gc0 + (wd<<1), gcb = gca + 1;
      _Float16 va = (_Float16)2.0f, vb = (_Float16)2.0f;
      if (rok && (unsigned)gca < (unsigned)IMG) va = (_Float16)sigmoidf(pred[base + (long)gr*IMG + gca]);
      if (rok && (unsigned)gcb < (unsigned)IMG) vb = (_Float16)sigmoidf(pred[base + (long)gr*IMG + gcb]);
      h2 w; w.x = va; w.y = vb;
      P[(1+r)*SPP + 2 + wd] = h2u(w);
    }
    for (int u=tid; u<264; u+=256){
      int r = u/3, w = u - r*3;
      int gr = gr0 + r;
      bool rok = (unsigned)gr < (unsigned)IMG;
      unsigned bits = 0;
      for (int b=0;b<32;++b){
        int c = (w<<5) + b;
        unsigned bit = 1;
        if (c < 88) {
          int gc = gc0 + c;
          if (rok && (unsigned)gc < (unsigned)IMG) bit = (unsigned)(targ[base+(long)gr*IMG+gc] != 0);
        }
        bits |= bit << b;
      }
      Ta[u] = bits;
    }
  }
  __syncthreads();

  // col validity masks (BND)
  unsigned cm0=~0u, cm1=~0u, cm2=0x00FFFFFFu;
  bool colO = false;
  if (BND) {
    int lo = (-gc0 > 0) ? -gc0 : 0;
    int hi = (IMG - gc0 < 88) ? (IMG - gc0) : 88;
    colO = (lo > 0) || (hi < 88);
    unsigned m[3];
    #pragma unroll
    for (int w=0; w<3; ++w){
      int l = lo - (w<<5); if (l<0) l=0;
      int h = hi - (w<<5); if (h>32) h=32;
      unsigned mm = 0;
      if (h > l) {
        unsigned top = (h>=32)? ~0u : ((1u<<h)-1u);
        unsigned bot = (l<=0)? 0u : ((1u<<l)-1u);
        mm = top & ~bot;
      }
      m[w]=mm;
    }
    cm0=m[0]; cm1=m[1]; cm2=m[2] & 0x00FFFFFF;
  }

  // erode ownership: 18 tall-5 strips x 12 quads = 216 units
  const bool eact0 = (tid < 216);
  const int es = tid / 12, eq = tid - es*12;
  const int s5 = es * 5;                 // first erode px row of strip
  const int ew = eq << 2;                // quad word 0..44 (includes pads at 0,1,46,47)
  // targ erode: word 3+u (rows 1..86 = words 3..260)
  const int to = 3 + tid;
  const int twd = tid - (tid/3)*3;
  const bool tex = (tid < 2);
  const int to2 = 259 + tid;
  const int twd2 = (256+tid) - ((256+tid)/3)*3;

  // interior ownership: 2 rows x 8 px per thread
  const int qc = tid & 7;
  const int rg = tid >> 3;
  const int r0 = HALO + (rg<<1);         // px rows 12..74
  const int wq = 8 + (qc<<2);            // words 8..36 (px 12..75)
  const int bp = 12 + (qc<<3);

  h2 ep[8];
  {
    uint4 a0 = *(const uint4*)&P[(r0+1)*SPP + wq];
    uint4 a1 = *(const uint4*)&P[(r0+2)*SPP + wq];
    ep[0]=u2h(a0.x); ep[1]=u2h(a0.y); ep[2]=u2h(a0.z); ep[3]=u2h(a0.w);
    ep[4]=u2h(a1.x); ep[5]=u2h(a1.y); ep[6]=u2h(a1.z); ep[7]=u2h(a1.w);
    #pragma unroll
    for (int i=0;i<8;++i){ val[i]=ep[i]; skel[i]=(h2)(_Float16)0.0f; }
  }
  {
    int oa = r0*3, ob = (r0+1)*3;
    tbits = extract8(Ta[oa],Ta[oa+1],Ta[oa+2],bp)
          | (extract8(Ta[ob],Ta[ob+1],Ta[ob+2],bp) << 8);
  }
  unsigned tp0=0,tp1=0,tp2=0, sk0=0,sk1=0,sk2=0;
  const bool td = (tid < 64);
  const int tro = (12 + tid)*3;
  if (td) { tp0=Ta[tro]; tp1=Ta[tro+1]; tp2=Ta[tro+2]; }

  const h2 onev  = {(_Float16)1.0f,(_Float16)1.0f};
  const h2 zerov = {(_Float16)0.0f,(_Float16)0.0f};

  for (int j=0;j<11;++j){
    // ---- erode reads + compute (in registers) ----
    uint4 e[5];
    const bool act = eact0 && (s5+4 >= j+1) && (s5 <= 86-j);
    if (act){
      uint4 rw[7];
      #pragma unroll
      for (int t=0;t<7;++t){
        int pr = s5 - 1 + t; pr = (pr > 88) ? 88 : pr;
        rw[t] = *(const uint4*)&P[(pr+1)*SPP + ew];
      }
      h2 lw[5], rv[5];
      #pragma unroll
      for (int t=0;t<5;++t){
        int pr = s5 + t; pr = (pr > 88) ? 88 : pr;
        lw[t] = u2h(P[(pr+1)*SPP + ew - 1]);   // pad/sentinel-safe
        rv[t] = u2h(P[(pr+1)*SPP + ew + 4]);
      }
      #pragma unroll
      for (int t=0;t<5;++t){
        h2 a0=u2h(rw[t+1].x), a1=u2h(rw[t+1].y), a2=u2h(rw[t+1].z), a3=u2h(rw[t+1].w);
        h2 v0=pmin(u2h(rw[t].x), u2h(rw[t+2].x));
        h2 v1=pmin(u2h(rw[t].y), u2h(rw[t+2].y));
        h2 v2=pmin(u2h(rw[t].z), u2h(rw[t+2].z));
        h2 v3=pmin(u2h(rw[t].w), u2h(rw[t+2].w));
        h2 f0=funnel(a0,lw[t]), f1=funnel(a1,a0), f2=funnel(a2,a1),
           f3=funnel(a3,a2), f4=funnel(rv[t],a3);
        e[t].x=h2u(pmin(pmin(f0,f1),pmin(v0,a0)));
        e[t].y=h2u(pmin(pmin(f1,f2),pmin(v1,a1)));
        e[t].z=h2u(pmin(pmin(f2,f3),pmin(v2,a2)));
        e[t].w=h2u(pmin(pmin(f3,f4),pmin(v3,a3)));
      }
    }
    // ---- targ erode (read+compute) ----
    unsigned tres, tres2;
    {
      unsigned own=Ta[to], up=Ta[to-3], dn=Ta[to+3];
      unsigned le = (twd>0)? Ta[to-1] : ~0u;
      unsigned ri = (twd<2)? Ta[to+1] : ~0u;
      unsigned h = own & ((own>>1)|(ri<<31)) & ((own<<1)|(le>>31));
      tres = h & up & dn;
    }
    if (tex){
      unsigned own=Ta[to2], up=Ta[to2-3], dn=Ta[to2+3];
      unsigned le = (twd2>0)? Ta[to2-1] : ~0u;
      unsigned ri = (twd2<2)? Ta[to2+1] : ~0u;
      unsigned h = own & ((own>>1)|(ri<<31)) & ((own<<1)|(le>>31));
      tres2 = h & up & dn;
    }
    __syncthreads();
    // ---- writes ----
    if (act){
      #pragma unroll
      for (int t=0;t<5;++t){
        int pr = s5 + t; pr = (pr > 88) ? 88 : pr;   // row 88 = guard, clobber OK
        *(uint4*)&P[(pr+1)*SPP + ew] = e[t];
      }
    }
    Ta[to] = tres;
    if (tex) Ta[to2] = tres2;
    __syncthreads();

    if (BND) {  // re-stamp OOB to erode-neutral sentinel
      if (gr0 < 0) {
        for (int i=tid;i<12*44;i+=256){ int r=i/44; P[(1+r)*SPP+2+(i-r*44)] = SEN2; }
        if (tid < 36) Ta[tid] = ~0u;
      }
      if (gr0 + 88 > IMG) {
        for (int i=tid;i<12*44;i+=256){ int r=i/44; P[(77+r)*SPP+2+(i-r*44)] = SEN2; }
        if (tid < 36) Ta[228+tid] = ~0u;
      }
      if (colO) {
        if (gc0 < 0)
          for (int i=tid;i<88*6;i+=256){ int r=i/6; P[(1+r)*SPP+2+(i-r*6)] = SEN2; }
        if (gc0 + 88 > IMG)
          for (int i=tid;i<88*6;i+=256){ int r=i/6; P[(1+r)*SPP+40+(i-r*6)] = SEN2; }
        for (int i=tid;i<264;i+=256){
          int r=i/3, w=i-r*3;
          unsigned nm = (w==0)?~cm0:((w==1)?~cm1:~cm2);
          Ta[i] |= nm;
        }
      }
      __syncthreads();
    }

    // ---- pred 3x3 dilate at own 2x8 px + skel update (reads P = e_j) ----
    h2 H[4][4];
    uint4 cap0, cap1;
    #pragma unroll
    for (int k=0;k<4;++k){
      int ro = (r0+k)*SPP + wq;              // px rows r0-1..r0+2
      uint4 c = *(const uint4*)&P[ro];
      h2 lwv = u2h(P[ro-1]);
      h2 rwv = u2h(P[ro+4]);
      if (k==1) cap0 = c;
      if (k==2) cap1 = c;
      h2 a0=u2h(c.x),a1=u2h(c.y),a2=u2h(c.z),a3=u2h(c.w);
      if (BND){
        a0=unsent(a0,onev,zerov); a1=unsent(a1,onev,zerov);
        a2=unsent(a2,onev,zerov); a3=unsent(a3,onev,zerov);
        lwv=unsent(lwv,onev,zerov); rwv=unsent(rwv,onev,zerov);
      }
      h2 f0=funnel(a0,lwv), f1=funnel(a1,a0), f2=funnel(a2,a1), f3=funnel(a3,a2), f4=funnel(rwv,a3);
      H[k][0]=pmax(pmax(f0,f1),a0);
      H[k][1]=pmax(pmax(f1,f2),a1);
      H[k][2]=pmax(pmax(f2,f3),a2);
      H[k][3]=pmax(pmax(f3,f4),a3);
    }
    #pragma unroll
    for (int i=0;i<4;++i){
      h2 m0 = pmax(pmax(H[0][i],H[1][i]),H[2][i]);
      h2 m1 = pmax(pmax(H[1][i],H[2][i]),H[3][i]);
      h2 d0 = pmax(ep[i]-m0, zerov);
      h2 d1 = pmax(ep[4+i]-m1, zerov);
      h2 x0 = d0 - skel[i]*d0;
      h2 x1 = d1 - skel[4+i]*d1;
      skel[i]   = skel[i]   + pmax(x0, zerov);
      skel[4+i] = skel[4+i] + pmax(x1, zerov);
    }
    ep[0]=u2h(cap0.x); ep[1]=u2h(cap0.y); ep[2]=u2h(cap0.z); ep[3]=u2h(cap0.w);
    ep[4]=u2h(cap1.x); ep[5]=u2h(cap1.y); ep[6]=u2h(cap1.z); ep[7]=u2h(cap1.w);

    // ---- targ dilate + skel_t ----
    if (td) {
      unsigned o0=Ta[tro], o1=Ta[tro+1], o2=Ta[tro+2];
      unsigned u0=Ta[tro-3], u1=Ta[tro-2], u2=Ta[tro-1];
      unsigned n0=Ta[tro+3], n1=Ta[tro+4], n2=Ta[tro+5];
      unsigned v0,v1,v2;
      if (BND){
        unsigned mu = ((unsigned)(gr0 + 11 + tid) < (unsigned)IMG) ? ~0u : 0u;
        unsigned md = ((unsigned)(gr0 + 13 + tid) < (unsigned)IMG) ? ~0u : 0u;
        v0 = ((u0&mu)|o0|(n0&md)) & cm0;
        v1 = ((u1&mu)|o1|(n1&md)) & cm1;
        v2 = ((u2&mu)|o2|(n2&md)) & cm2;
      } else {
        v0 = u0|o0|n0; v1 = u1|o1|n1; v2 = u2|o2|n2;
      }
      unsigned d0 = v0 | (v0<<1) | (v0>>1) | (v1<<31);
      unsigned d1 = v1 | (v1<<1) | (v0>>31) | (v1>>1) | (v2<<31);
      unsigned d2 = v2 | (v2<<1) | (v1>>31) | (v2>>1);
      sk0 |= tp0 & ~d0;
      sk1 |= tp1 & ~d1;
      sk2 |= tp2 & ~d2;
      tp0 = o0; tp1 = o1; tp2 = o2;
    }
  }

  __syncthreads();
  if (td){ Ta[3*tid]=sk0; Ta[3*tid+1]=sk1; Ta[3*tid+2]=sk2; }
  __syncthreads();
  {
    int o = (r0-12)*3;
    skbits = extract8(Ta[o],Ta[o+1],Ta[o+2],bp)
           | (extract8(Ta[o+3],Ta[o+4],Ta[o+5],bp) << 8);
  }
}

__global__ __launch_bounds__(256,8)
void cl_dice_main(const float* __restrict__ pred, const int* __restrict__ targ,
                  float* __restrict__ ws) {
  __shared__ alignas(16) unsigned sP[NPRED];
  __shared__ unsigned sTA[264];
  const int tid = threadIdx.x;
  const int gr0 = blockIdx.y * TILE - HALO;
  const int gc0 = blockIdx.x * TILE - HALO;
  const long base = (long)blockIdx.z * (long)(IMG * IMG);

  h2 val[8], skel[8]; unsigned tbits, skbits;
  const bool bnd = (blockIdx.x == 0) | (blockIdx.x == gridDim.x - 1) |
                   (blockIdx.y == 0) | (blockIdx.y == gridDim.y - 1);
  if (!bnd) pipeline<false>(pred, targ, base, gr0, gc0, tid, sP, sTA, val, skel, tbits, skbits);
  else      pipeline<true >(pred, targ, base, gr0, gc0, tid, sP, sTA, val, skel, tbits, skbits);

  float s[7] = {0,0,0,0,0,0,0};
  #pragma unroll
  for (int k=0;k<8;++k){
    int bb = ((k>>2)<<3) + ((k&3)<<1);
    float p0=(float)val[k].x,  p1=(float)val[k].y;
    float a0=(float)skel[k].x, a1=(float)skel[k].y;
    float t0=(float)((tbits>>bb)&1u),  t1=(float)((tbits>>(bb+1))&1u);
    float b0=(float)((skbits>>bb)&1u), b1=(float)((skbits>>(bb+1))&1u);
    s[0]+=a0+a1;        s[1]+=a0*t0+a1*t1;
    s[2]+=b0+b1;        s[3]+=b0*p0+b1*p1;
    s[4]+=p0*t0+p1*t1;  s[5]+=p0+p1;  s[6]+=t0+t1;
  }

  float* red = (float*)sP;
  #pragma unroll
  for (int k=0;k<7;++k){
    float v = s[k];
    v += __shfl_down(v,32); v += __shfl_down(v,16); v += __shfl_down(v,8);
    v += __shfl_down(v,4);  v += __shfl_down(v,2);  v += __shfl_down(v,1);
    if ((tid & 63) == 0) red[(tid>>6)*8 + k] = v;
  }
  __syncthreads();
  if (tid < 7) {
    float v = red[tid] + red[8+tid] + red[16+tid] + red[24+tid];
    int blk = (blockIdx.z * gridDim.y + blockIdx.y) * gridDim.x + blockIdx.x;
    ws[blk*8 + tid] = v;
  }
}

__global__ __launch_bounds__(256)
void cl_dice_finalize(const float* __restrict__ ws, float* __restrict__ out, int nblk) {
  __shared__ float red[4][8];
  int tid = threadIdx.x;
  float acc[7] = {0,0,0,0,0,0,0};
  for (int i=tid; i<nblk; i+=256) {
    #pragma unroll
    for (int k=0;k<7;++k) acc[k] += ws[i*8 + k];
  }
  #pragma unroll
  for (int k=0;k<7;++k){
    float v = acc[k];
    v += __shfl_down(v,32); v += __shfl_down(v,16); v += __shfl_down(v,8);
    v += __shfl_down(v,4);  v += __shfl_down(v,2);  v += __shfl_down(v,1);
    if ((tid & 63) == 0) red[tid>>6][k] = v;
  }
  __syncthreads();
  if (tid == 0) {
    float t0[7];
    #pragma unroll
    for (int k=0;k<7;++k) t0[k] = red[0][k] + red[1][k] + red[2][k] + red[3][k];
    float sum_sp = t0[0], sum_spt = t0[1], sum_st = t0[2], sum_stp = t0[3];
    float inter  = t0[4], sum_p   = t0[5], sum_t  = t0[6];
    float tprec = (sum_spt + 1.0f) / (sum_sp + 1.0f);
    float tsens = (sum_stp + 1.0f) / (sum_st + 1.0f);
    float cl    = 2.0f * tprec * tsens / (tprec + tsens + 1e-7f);
    float dice  = (2.0f * inter + 1.0f) / (sum_p + sum_t + 1.0f);
    out[0] = 1.0f - 0.5f * (dice + cl);
  }
}

extern "C" void kernel_launch(void* const* d_in, const int* in_sizes, int n_in,
                              void* d_out, int out_size, void* d_ws, size_t ws_size,
                              hipStream_t stream) {
  const float* pred = (const float*)d_in[0];
  const int*   targ = (const int*)d_in[1];
  float* ws  = (float*)d_ws;
  float* out = (float*)d_out;

  const int B = in_sizes[0] / (IMG * IMG);     // 8
  dim3 grid(IMG / TILE, IMG / TILE, B);        // 16 x 16 x 8 = 2048 blocks
  cl_dice_main<<<grid, 256, 0, stream>>>(pred, targ, ws);

  const int nblk = (IMG / TILE) * (IMG / TILE) * B;
  cl_dice_finalize<<<1, 256, 0, stream>>>(ws, out, nblk);
}

// Round 10
// 287.227 us; speedup vs baseline: 1.1186x; 1.1186x over previous
//
#include <hip/hip_runtime.h>
#include <math.h>

#define IMG  1024
#define TILE 64
#define HALO 12
#define SPP  52              // words/row: 2 pad + 44 data (words 2..45) + 6 pad (46..51)
#define NPRED (90*SPP)       // buffer rows 0..89 = px rows -1..88 (guard top/bottom)
#define SEN2 0x40004000u     // (2.0h,2.0h) sentinel = +inf (all real values <= 1)

// pred: fp16 pair-packed 2 px/word, single LDS buffer, in-place erode
// (read-all -> barrier -> write-all). targ: binary bit-packed 32 px/word.
typedef _Float16 h2 __attribute__((ext_vector_type(2)));
union UH { unsigned u; h2 h; };
__device__ __forceinline__ h2 u2h(unsigned u){ UH x; x.u=u; return x.h; }
__device__ __forceinline__ unsigned h2u(h2 h){ UH x; x.h=h; return x.u; }
__device__ __forceinline__ h2 pmin(h2 a, h2 b){ return __builtin_elementwise_min(a,b); }
__device__ __forceinline__ h2 pmax(h2 a, h2 b){ return __builtin_elementwise_max(a,b); }
__device__ __forceinline__ h2 funnel(h2 hi_src, h2 lo_src){
  return u2h((h2u(lo_src)>>16) | (h2u(hi_src)<<16));
}
__device__ __forceinline__ float sigmoidf(float x){ return 1.0f/(1.0f+__expf(-x)); }
__device__ __forceinline__ h2 unsent(h2 x, h2 onev, h2 zerov){
  h2 t = pmax(x-onev, zerov); return x - t - t;   // 2.0 -> 0, identity on [0,1]
}
__device__ __forceinline__ unsigned extract8(unsigned w0, unsigned w1, unsigned w2, int bp){
  unsigned long long lo = (unsigned long long)w0 | ((unsigned long long)w1<<32);
  unsigned long long hi = (unsigned long long)w1 | ((unsigned long long)w2<<32);
  unsigned a = (unsigned)(lo >> bp);
  unsigned b = (unsigned)(hi >> (bp & 31));
  return ((bp < 32) ? a : b) & 0xFFu;
}
// 5-pt cross erode of one 8-px quad row: center rm/rc/rn, left/right edge words
__device__ __forceinline__ uint4 erode5(uint4 rm, uint4 rc, uint4 rn, h2 lw, h2 rv){
  h2 a0=u2h(rc.x), a1=u2h(rc.y), a2=u2h(rc.z), a3=u2h(rc.w);
  h2 v0=pmin(u2h(rm.x), u2h(rn.x));
  h2 v1=pmin(u2h(rm.y), u2h(rn.y));
  h2 v2=pmin(u2h(rm.z), u2h(rn.z));
  h2 v3=pmin(u2h(rm.w), u2h(rn.w));
  h2 f0=funnel(a0,lw), f1=funnel(a1,a0), f2=funnel(a2,a1), f3=funnel(a3,a2), f4=funnel(rv,a3);
  uint4 e;
  e.x=h2u(pmin(pmin(f0,f1),pmin(v0,a0)));
  e.y=h2u(pmin(pmin(f1,f2),pmin(v1,a1)));
  e.z=h2u(pmin(pmin(f2,f3),pmin(v2,a2)));
  e.w=h2u(pmin(pmin(f3,f4),pmin(v3,a3)));
  return e;
}

template<bool BND>
__device__ void pipeline(const float* __restrict__ pred, const int* __restrict__ targ,
                         long base, int gr0, int gc0, int tid,
                         unsigned* P, unsigned* Ta,
                         h2 val[8], h2 skel[8], unsigned &tbits, unsigned &skbits) {
  // ---- stamp guard rows (px -1, 88) and pad cols {0,1,46..51} ----
  for (int i = tid; i < 104; i += 256) {
    int r = (i < 52) ? 0 : 89, c = (i < 52) ? i : i - 52;
    P[r*SPP + c] = SEN2;
  }
  for (int i = tid; i < 704; i += 256) {
    int r = 1 + (i >> 3), w = i & 7;
    w = (w < 2) ? w : 44 + w;
    P[r*SPP + w] = SEN2;
  }
  // ---- global -> LDS ----
  if (!BND) {
    #pragma unroll
    for (int k=0;k<4;++k){
      int u = tid + (k<<8);
      if (u < 968){                          // 88 rows x 11 groups of 8 px
        int r = u/11, q = u - r*11;
        long g = base + (long)(gr0+r)*IMG + gc0 + (q<<3);
        float4 pa = *(const float4*)(pred+g);
        float4 pb = *(const float4*)(pred+g+4);
        h2 w0 = {(_Float16)sigmoidf(pa.x), (_Float16)sigmoidf(pa.y)};
        h2 w1 = {(_Float16)sigmoidf(pa.z), (_Float16)sigmoidf(pa.w)};
        h2 w2 = {(_Float16)sigmoidf(pb.x), (_Float16)sigmoidf(pb.y)};
        h2 w3 = {(_Float16)sigmoidf(pb.z), (_Float16)sigmoidf(pb.w)};
        int o = (1+r)*SPP + 2 + (q<<2);
        uint2 d0; d0.x=h2u(w0); d0.y=h2u(w1);
        uint2 d1; d1.x=h2u(w2); d1.y=h2u(w3);
        *(uint2*)&P[o]   = d0;
        *(uint2*)&P[o+2] = d1;
      }
    }
    #pragma unroll
    for (int k=0;k<2;++k){
      int u = tid + (k<<8);
      if (u < 264){                          // 88 rows x 3 bit-words
        int r = u/3, w = u - r*3;
        long g = base + (long)(gr0+r)*IMG + gc0 + (w<<5);
        unsigned bits = 0;
        #pragma unroll
        for (int i=0;i<8;++i){
          if (w < 2 || i < 6) {
            int4 tv = *(const int4*)(targ + g + (i<<2));
            unsigned nib = (unsigned)(tv.x!=0) | ((unsigned)(tv.y!=0)<<1)
                         | ((unsigned)(tv.z!=0)<<2) | ((unsigned)(tv.w!=0)<<3);
            bits |= nib << (i<<2);
          }
        }
        if (w==2) bits |= 0xFF000000u;       // pseudo px 88..95: erode-neutral 1
        Ta[u] = bits;
      }
    }
  } else {
    for (int i=tid; i<88*44; i+=256){
      int r = i/44, wd = i - r*44;
      int gr = gr0 + r;
      bool rok = (unsigned)gr < (unsigned)IMG;
      int gca = gc0 + (wd<<1), gcb = gca + 1;
      _Float16 va = (_Float16)2.0f, vb = (_Float16)2.0f;
      if (rok && (unsigned)gca < (unsigned)IMG) va = (_Float16)sigmoidf(pred[base + (long)gr*IMG + gca]);
      if (rok && (unsigned)gcb < (unsigned)IMG) vb = (_Float16)sigmoidf(pred[base + (long)gr*IMG + gcb]);
      h2 w; w.x = va; w.y = vb;
      P[(1+r)*SPP + 2 + wd] = h2u(w);
    }
    for (int u=tid; u<264; u+=256){
      int r = u/3, w = u - r*3;
      int gr = gr0 + r;
      bool rok = (unsigned)gr < (unsigned)IMG;
      unsigned bits = 0;
      for (int b=0;b<32;++b){
        int c = (w<<5) + b;
        unsigned bit = 1;
        if (c < 88) {
          int gc = gc0 + c;
          if (rok && (unsigned)gc < (unsigned)IMG) bit = (unsigned)(targ[base+(long)gr*IMG+gc] != 0);
        }
        bits |= bit << b;
      }
      Ta[u] = bits;
    }
  }
  __syncthreads();

  // col validity masks (BND)
  unsigned cm0=~0u, cm1=~0u, cm2=0x00FFFFFFu;
  bool colO = false;
  if (BND) {
    int lo = (-gc0 > 0) ? -gc0 : 0;
    int hi = (IMG - gc0 < 88) ? (IMG - gc0) : 88;
    colO = (lo > 0) || (hi < 88);
    unsigned m[3];
    #pragma unroll
    for (int w=0; w<3; ++w){
      int l = lo - (w<<5); if (l<0) l=0;
      int h = hi - (w<<5); if (h>32) h=32;
      unsigned mm = 0;
      if (h > l) {
        unsigned top = (h>=32)? ~0u : ((1u<<h)-1u);
        unsigned bot = (l<=0)? 0u : ((1u<<l)-1u);
        mm = top & ~bot;
      }
      m[w]=mm;
    }
    cm0=m[0]; cm1=m[1]; cm2=m[2] & 0x00FFFFFF;
  }

  // erode ownership: 18 tall-5 strips x 12 quads = 216 units
  const bool eact0 = (tid < 216);
  const int es = tid / 12, eq = tid - es*12;
  const int s5 = es * 5;                 // first erode px row of strip
  const int ew = eq << 2;                // quad word 0,4,...,44
  // targ erode: word 3+u (rows 1..86 = words 3..260)
  const int to = 3 + tid;
  const int twd = tid - (tid/3)*3;
  const bool tex = (tid < 2);
  const int to2 = 259 + tid;
  const int twd2 = (256+tid) - ((256+tid)/3)*3;

  // interior ownership: 2 rows x 8 px per thread
  const int qc = tid & 7;
  const int rg = tid >> 3;
  const int r0 = HALO + (rg<<1);         // px rows 12..74
  const int wq = 8 + (qc<<2);            // words 8..36 (px 12..75)
  const int bp = 12 + (qc<<3);

  h2 ep[8];
  {
    uint4 a0 = *(const uint4*)&P[(r0+1)*SPP + wq];
    uint4 a1 = *(const uint4*)&P[(r0+2)*SPP + wq];
    ep[0]=u2h(a0.x); ep[1]=u2h(a0.y); ep[2]=u2h(a0.z); ep[3]=u2h(a0.w);
    ep[4]=u2h(a1.x); ep[5]=u2h(a1.y); ep[6]=u2h(a1.z); ep[7]=u2h(a1.w);
    #pragma unroll
    for (int i=0;i<8;++i){ val[i]=ep[i]; skel[i]=(h2)(_Float16)0.0f; }
  }
  {
    int oa = r0*3, ob = (r0+1)*3;
    tbits = extract8(Ta[oa],Ta[oa+1],Ta[oa+2],bp)
          | (extract8(Ta[ob],Ta[ob+1],Ta[ob+2],bp) << 8);
  }
  unsigned tp0=0,tp1=0,tp2=0, sk0=0,sk1=0,sk2=0;
  const bool td = (tid < 64);
  const int tro = (12 + tid)*3;
  if (td) { tp0=Ta[tro]; tp1=Ta[tro+1]; tp2=Ta[tro+2]; }

  const h2 onev  = {(_Float16)1.0f,(_Float16)1.0f};
  const h2 zerov = {(_Float16)0.0f,(_Float16)0.0f};

  for (int j=0;j<11;++j){
    // ---- erode reads + compute (rolling 3-row window, results in regs) ----
    uint4 e[5];
    const bool act = eact0 && (s5+4 >= j+1) && (s5 <= 86-j);
    if (act){
      uint4 rm = *(const uint4*)&P[s5*SPP + ew];         // px row s5-1
      uint4 rc = *(const uint4*)&P[(s5+1)*SPP + ew];     // px row s5
      #pragma unroll
      for (int t=0;t<5;++t){
        int brn = s5 + 2 + t; brn = (brn > 89) ? 89 : brn;
        uint4 rn = *(const uint4*)&P[brn*SPP + ew];
        int brc = s5 + 1 + t; brc = (brc > 89) ? 89 : brc;
        h2 lw = u2h(P[brc*SPP + ew - 1]);
        h2 rv = u2h(P[brc*SPP + ew + 4]);
        e[t] = erode5(rm, rc, rn, lw, rv);
        rm = rc; rc = rn;
      }
    }
    // ---- targ erode (read+compute) ----
    unsigned tres, tres2;
    {
      unsigned own=Ta[to], up=Ta[to-3], dn=Ta[to+3];
      unsigned le = (twd>0)? Ta[to-1] : ~0u;
      unsigned ri = (twd<2)? Ta[to+1] : ~0u;
      unsigned h = own & ((own>>1)|(ri<<31)) & ((own<<1)|(le>>31));
      tres = h & up & dn;
    }
    if (tex){
      unsigned own=Ta[to2], up=Ta[to2-3], dn=Ta[to2+3];
      unsigned le = (twd2>0)? Ta[to2-1] : ~0u;
      unsigned ri = (twd2<2)? Ta[to2+1] : ~0u;
      unsigned h = own & ((own>>1)|(ri<<31)) & ((own<<1)|(le>>31));
      tres2 = h & up & dn;
    }
    __syncthreads();
    // ---- writes ----
    if (act){
      #pragma unroll
      for (int t=0;t<5;++t){
        int br = s5 + 1 + t; br = (br > 89) ? 89 : br;   // row 89 = guard, clobber OK
        *(uint4*)&P[br*SPP + ew] = e[t];
      }
    }
    Ta[to] = tres;
    if (tex) Ta[to2] = tres2;
    __syncthreads();

    if (BND) {  // re-stamp OOB to erode-neutral sentinel
      if (gr0 < 0) {
        for (int i=tid;i<12*44;i+=256){ int r=i/44; P[(1+r)*SPP+2+(i-r*44)] = SEN2; }
        if (tid < 36) Ta[tid] = ~0u;
      }
      if (gr0 + 88 > IMG) {
        for (int i=tid;i<12*44;i+=256){ int r=i/44; P[(77+r)*SPP+2+(i-r*44)] = SEN2; }
        if (tid < 36) Ta[228+tid] = ~0u;
      }
      if (colO) {
        if (gc0 < 0)
          for (int i=tid;i<88*6;i+=256){ int r=i/6; P[(1+r)*SPP+2+(i-r*6)] = SEN2; }
        if (gc0 + 88 > IMG)
          for (int i=tid;i<88*6;i+=256){ int r=i/6; P[(1+r)*SPP+40+(i-r*6)] = SEN2; }
        for (int i=tid;i<264;i+=256){
          int r=i/3, w=i-r*3;
          unsigned nm = (w==0)?~cm0:((w==1)?~cm1:~cm2);
          Ta[i] |= nm;
        }
      }
      __syncthreads();
    }

    // ---- pred 3x3 dilate at own 2x8 px + skel update (reads P = e_j) ----
    h2 H[4][4];
    uint4 cap0, cap1;
    #pragma unroll
    for (int k=0;k<4;++k){
      int ro = (r0+k)*SPP + wq;              // px rows r0-1..r0+2
      uint4 c = *(const uint4*)&P[ro];
      h2 lwv = u2h(P[ro-1]);
      h2 rwv = u2h(P[ro+4]);
      if (k==1) cap0 = c;
      if (k==2) cap1 = c;
      h2 a0=u2h(c.x),a1=u2h(c.y),a2=u2h(c.z),a3=u2h(c.w);
      if (BND){
        a0=unsent(a0,onev,zerov); a1=unsent(a1,onev,zerov);
        a2=unsent(a2,onev,zerov); a3=unsent(a3,onev,zerov);
        lwv=unsent(lwv,onev,zerov); rwv=unsent(rwv,onev,zerov);
      }
      h2 f0=funnel(a0,lwv), f1=funnel(a1,a0), f2=funnel(a2,a1), f3=funnel(a3,a2), f4=funnel(rwv,a3);
      H[k][0]=pmax(pmax(f0,f1),a0);
      H[k][1]=pmax(pmax(f1,f2),a1);
      H[k][2]=pmax(pmax(f2,f3),a2);
      H[k][3]=pmax(pmax(f3,f4),a3);
    }
    #pragma unroll
    for (int i=0;i<4;++i){
      h2 m0 = pmax(pmax(H[0][i],H[1][i]),H[2][i]);
      h2 m1 = pmax(pmax(H[1][i],H[2][i]),H[3][i]);
      h2 d0 = pmax(ep[i]-m0, zerov);
      h2 d1 = pmax(ep[4+i]-m1, zerov);
      h2 x0 = d0 - skel[i]*d0;
      h2 x1 = d1 - skel[4+i]*d1;
      skel[i]   = skel[i]   + pmax(x0, zerov);
      skel[4+i] = skel[4+i] + pmax(x1, zerov);
    }
    ep[0]=u2h(cap0.x); ep[1]=u2h(cap0.y); ep[2]=u2h(cap0.z); ep[3]=u2h(cap0.w);
    ep[4]=u2h(cap1.x); ep[5]=u2h(cap1.y); ep[6]=u2h(cap1.z); ep[7]=u2h(cap1.w);

    // ---- targ dilate + skel_t ----
    if (td) {
      unsigned o0=Ta[tro], o1=Ta[tro+1], o2=Ta[tro+2];
      unsigned u0=Ta[tro-3], u1=Ta[tro-2], u2=Ta[tro-1];
      unsigned n0=Ta[tro+3], n1=Ta[tro+4], n2=Ta[tro+5];
      unsigned v0,v1,v2;
      if (BND){
        unsigned mu = ((unsigned)(gr0 + 11 + tid) < (unsigned)IMG) ? ~0u : 0u;
        unsigned md = ((unsigned)(gr0 + 13 + tid) < (unsigned)IMG) ? ~0u : 0u;
        v0 = ((u0&mu)|o0|(n0&md)) & cm0;
        v1 = ((u1&mu)|o1|(n1&md)) & cm1;
        v2 = ((u2&mu)|o2|(n2&md)) & cm2;
      } else {
        v0 = u0|o0|n0; v1 = u1|o1|n1; v2 = u2|o2|n2;
      }
      unsigned d0 = v0 | (v0<<1) | (v0>>1) | (v1<<31);
      unsigned d1 = v1 | (v1<<1) | (v0>>31) | (v1>>1) | (v2<<31);
      unsigned d2 = v2 | (v2<<1) | (v1>>31) | (v2>>1);
      sk0 |= tp0 & ~d0;
      sk1 |= tp1 & ~d1;
      sk2 |= tp2 & ~d2;
      tp0 = o0; tp1 = o1; tp2 = o2;
    }
  }

  __syncthreads();
  if (td){ Ta[3*tid]=sk0; Ta[3*tid+1]=sk1; Ta[3*tid+2]=sk2; }
  __syncthreads();
  {
    int o = (r0-12)*3;
    skbits = extract8(Ta[o],Ta[o+1],Ta[o+2],bp)
           | (extract8(Ta[o+3],Ta[o+4],Ta[o+5],bp) << 8);
  }
}

__global__ __launch_bounds__(256,6)
void cl_dice_main(const float* __restrict__ pred, const int* __restrict__ targ,
                  float* __restrict__ ws) {
  __shared__ alignas(16) unsigned sP[NPRED];
  __shared__ unsigned sTA[264];
  const int tid = threadIdx.x;
  const int gr0 = blockIdx.y * TILE - HALO;
  const int gc0 = blockIdx.x * TILE - HALO;
  const long base = (long)blockIdx.z * (long)(IMG * IMG);

  h2 val[8], skel[8]; unsigned tbits, skbits;
  const bool bnd = (blockIdx.x == 0) | (blockIdx.x == gridDim.x - 1) |
                   (blockIdx.y == 0) | (blockIdx.y == gridDim.y - 1);
  if (!bnd) pipeline<false>(pred, targ, base, gr0, gc0, tid, sP, sTA, val, skel, tbits, skbits);
  else      pipeline<true >(pred, targ, base, gr0, gc0, tid, sP, sTA, val, skel, tbits, skbits);

  float s[7] = {0,0,0,0,0,0,0};
  #pragma unroll
  for (int k=0;k<8;++k){
    int bb = ((k>>2)<<3) + ((k&3)<<1);
    float p0=(float)val[k].x,  p1=(float)val[k].y;
    float a0=(float)skel[k].x, a1=(float)skel[k].y;
    float t0=(float)((tbits>>bb)&1u),  t1=(float)((tbits>>(bb+1))&1u);
    float b0=(float)((skbits>>bb)&1u), b1=(float)((skbits>>(bb+1))&1u);
    s[0]+=a0+a1;        s[1]+=a0*t0+a1*t1;
    s[2]+=b0+b1;        s[3]+=b0*p0+b1*p1;
    s[4]+=p0*t0+p1*t1;  s[5]+=p0+p1;  s[6]+=t0+t1;
  }

  float* red = (float*)sP;
  #pragma unroll
  for (int k=0;k<7;++k){
    float v = s[k];
    v += __shfl_down(v,32); v += __shfl_down(v,16); v += __shfl_down(v,8);
    v += __shfl_down(v,4);  v += __shfl_down(v,2);  v += __shfl_down(v,1);
    if ((tid & 63) == 0) red[(tid>>6)*8 + k] = v;
  }
  __syncthreads();
  if (tid < 7) {
    float v = red[tid] + red[8+tid] + red[16+tid] + red[24+tid];
    int blk = (blockIdx.z * gridDim.y + blockIdx.y) * gridDim.x + blockIdx.x;
    ws[blk*8 + tid] = v;
  }
}

__global__ __launch_bounds__(256)
void cl_dice_finalize(const float* __restrict__ ws, float* __restrict__ out, int nblk) {
  __shared__ float red[4][8];
  int tid = threadIdx.x;
  float acc[7] = {0,0,0,0,0,0,0};
  for (int i=tid; i<nblk; i+=256) {
    #pragma unroll
    for (int k=0;k<7;++k) acc[k] += ws[i*8 + k];
  }
  #pragma unroll
  for (int k=0;k<7;++k){
    float v = acc[k];
    v += __shfl_down(v,32); v += __shfl_down(v,16); v += __shfl_down(v,8);
    v += __shfl_down(v,4);  v += __shfl_down(v,2);  v += __shfl_down(v,1);
    if ((tid & 63) == 0) red[tid>>6][k] = v;
  }
  __syncthreads();
  if (tid == 0) {
    float t0[7];
    #pragma unroll
    for (int k=0;k<7;++k) t0[k] = red[0][k] + red[1][k] + red[2][k] + red[3][k];
    float sum_sp = t0[0], sum_spt = t0[1], sum_st = t0[2], sum_stp = t0[3];
    float inter  = t0[4], sum_p   = t0[5], sum_t  = t0[6];
    float tprec = (sum_spt + 1.0f) / (sum_sp + 1.0f);
    float tsens = (sum_stp + 1.0f) / (sum_st + 1.0f);
    float cl    = 2.0f * tprec * tsens / (tprec + tsens + 1e-7f);
    float dice  = (2.0f * inter + 1.0f) / (sum_p + sum_t + 1.0f);
    out[0] = 1.0f - 0.5f * (dice + cl);
  }
}

extern "C" void kernel_launch(void* const* d_in, const int* in_sizes, int n_in,
                              void* d_out, int out_size, void* d_ws, size_t ws_size,
                              hipStream_t stream) {
  const float* pred = (const float*)d_in[0];
  const int*   targ = (const int*)d_in[1];
  float* ws  = (float*)d_ws;
  float* out = (float*)d_out;

  const int B = in_sizes[0] / (IMG * IMG);     // 8
  dim3 grid(IMG / TILE, IMG / TILE, B);        // 16 x 16 x 8 = 2048 blocks
  cl_dice_main<<<grid, 256, 0, stream>>>(pred, targ, ws);

  const int nblk = (IMG / TILE) * (IMG / TILE) * B;
  cl_dice_finalize<<<1, 256, 0, stream>>>(ws, out, nblk);
}

// Round 11
// 247.684 us; speedup vs baseline: 1.2972x; 1.1597x over previous
//
#include <hip/hip_runtime.h>
#include <math.h>

#define IMG  1024
#define TILE 64
#define HALO 12
#define SPP  52              // words/row: 2 pad + 44 data (words 2..45) + 6 pad (46..51)
#define NPRED (90*SPP)       // buffer rows 0..89 = px rows -1..88 (guard top/bottom)
#define SEN2 0x40004000u     // (2.0h,2.0h) sentinel = +inf (all real values <= 1)

// pred: fp16 pair-packed 2 px/word, single LDS buffer, in-place erode
// (read-all -> barrier -> write-all). targ: binary bit-packed 32 px/word.
typedef _Float16 h2 __attribute__((ext_vector_type(2)));
union UH { unsigned u; h2 h; };
__device__ __forceinline__ h2 u2h(unsigned u){ UH x; x.u=u; return x.h; }
__device__ __forceinline__ unsigned h2u(h2 h){ UH x; x.h=h; return x.u; }
__device__ __forceinline__ h2 pmin(h2 a, h2 b){ return __builtin_elementwise_min(a,b); }
__device__ __forceinline__ h2 pmax(h2 a, h2 b){ return __builtin_elementwise_max(a,b); }
__device__ __forceinline__ h2 funnel(h2 hi_src, h2 lo_src){
  return u2h((h2u(lo_src)>>16) | (h2u(hi_src)<<16));
}
__device__ __forceinline__ float sigmoidf(float x){ return 1.0f/(1.0f+__expf(-x)); }
__device__ __forceinline__ h2 unsent(h2 x, h2 onev, h2 zerov){
  h2 t = pmax(x-onev, zerov); return x - t - t;   // 2.0 -> 0, identity on [0,1]
}
__device__ __forceinline__ unsigned extract8(unsigned w0, unsigned w1, unsigned w2, int bp){
  unsigned long long lo = (unsigned long long)w0 | ((unsigned long long)w1<<32);
  unsigned long long hi = (unsigned long long)w1 | ((unsigned long long)w2<<32);
  unsigned a = (unsigned)(lo >> bp);
  unsigned b = (unsigned)(hi >> (bp & 31));
  return ((bp < 32) ? a : b) & 0xFFu;
}
// 5-pt cross erode of one 8-px quad row: center rm/rc/rn, left/right edge words
__device__ __forceinline__ uint4 erode5(uint4 rm, uint4 rc, uint4 rn, h2 lw, h2 rv){
  h2 a0=u2h(rc.x), a1=u2h(rc.y), a2=u2h(rc.z), a3=u2h(rc.w);
  h2 v0=pmin(u2h(rm.x), u2h(rn.x));
  h2 v1=pmin(u2h(rm.y), u2h(rn.y));
  h2 v2=pmin(u2h(rm.z), u2h(rn.z));
  h2 v3=pmin(u2h(rm.w), u2h(rn.w));
  h2 f0=funnel(a0,lw), f1=funnel(a1,a0), f2=funnel(a2,a1), f3=funnel(a3,a2), f4=funnel(rv,a3);
  uint4 e;
  e.x=h2u(pmin(pmin(f0,f1),pmin(v0,a0)));
  e.y=h2u(pmin(pmin(f1,f2),pmin(v1,a1)));
  e.z=h2u(pmin(pmin(f2,f3),pmin(v2,a2)));
  e.w=h2u(pmin(pmin(f3,f4),pmin(v3,a3)));
  return e;
}

template<bool BND>
__device__ void pipeline(const float* __restrict__ pred, const int* __restrict__ targ,
                         long base, int gr0, int gc0, int tid,
                         unsigned* P, unsigned* Ta,
                         h2 val[8], h2 skel[8], unsigned &tbits, unsigned &skbits) {
  // ---- stamp guard rows (px -1, 88) and pad cols {0,1,46..51} ----
  for (int i = tid; i < 104; i += 256) {
    int r = (i < 52) ? 0 : 89, c = (i < 52) ? i : i - 52;
    P[r*SPP + c] = SEN2;
  }
  for (int i = tid; i < 704; i += 256) {
    int r = 1 + (i >> 3), w = i & 7;
    w = (w < 2) ? w : 44 + w;
    P[r*SPP + w] = SEN2;
  }
  // ---- global -> LDS ----
  if (!BND) {
    #pragma unroll
    for (int k=0;k<4;++k){
      int u = tid + (k<<8);
      if (u < 968){                          // 88 rows x 11 groups of 8 px
        int r = u/11, q = u - r*11;
        long g = base + (long)(gr0+r)*IMG + gc0 + (q<<3);
        float4 pa = *(const float4*)(pred+g);
        float4 pb = *(const float4*)(pred+g+4);
        h2 w0 = {(_Float16)sigmoidf(pa.x), (_Float16)sigmoidf(pa.y)};
        h2 w1 = {(_Float16)sigmoidf(pa.z), (_Float16)sigmoidf(pa.w)};
        h2 w2 = {(_Float16)sigmoidf(pb.x), (_Float16)sigmoidf(pb.y)};
        h2 w3 = {(_Float16)sigmoidf(pb.z), (_Float16)sigmoidf(pb.w)};
        int o = (1+r)*SPP + 2 + (q<<2);
        uint2 d0; d0.x=h2u(w0); d0.y=h2u(w1);
        uint2 d1; d1.x=h2u(w2); d1.y=h2u(w3);
        *(uint2*)&P[o]   = d0;
        *(uint2*)&P[o+2] = d1;
      }
    }
    #pragma unroll
    for (int k=0;k<2;++k){
      int u = tid + (k<<8);
      if (u < 264){                          // 88 rows x 3 bit-words
        int r = u/3, w = u - r*3;
        long g = base + (long)(gr0+r)*IMG + gc0 + (w<<5);
        unsigned bits = 0;
        #pragma unroll
        for (int i=0;i<8;++i){
          if (w < 2 || i < 6) {
            int4 tv = *(const int4*)(targ + g + (i<<2));
            unsigned nib = (unsigned)(tv.x!=0) | ((unsigned)(tv.y!=0)<<1)
                         | ((unsigned)(tv.z!=0)<<2) | ((unsigned)(tv.w!=0)<<3);
            bits |= nib << (i<<2);
          }
        }
        if (w==2) bits |= 0xFF000000u;       // pseudo px 88..95: erode-neutral 1
        Ta[u] = bits;
      }
    }
  } else {
    for (int i=tid; i<88*44; i+=256){
      int r = i/44, wd = i - r*44;
      int gr = gr0 + r;
      bool rok = (unsigned)gr < (unsigned)IMG;
      int gca = gc0 + (wd<<1), gcb = gca + 1;
      _Float16 va = (_Float16)2.0f, vb = (_Float16)2.0f;
      if (rok && (unsigned)gca < (unsigned)IMG) va = (_Float16)sigmoidf(pred[base + (long)gr*IMG + gca]);
      if (rok && (unsigned)gcb < (unsigned)IMG) vb = (_Float16)sigmoidf(pred[base + (long)gr*IMG + gcb]);
      h2 w; w.x = va; w.y = vb;
      P[(1+r)*SPP + 2 + wd] = h2u(w);
    }
    for (int u=tid; u<264; u+=256){
      int r = u/3, w = u - r*3;
      int gr = gr0 + r;
      bool rok = (unsigned)gr < (unsigned)IMG;
      unsigned bits = 0;
      for (int b=0;b<32;++b){
        int c = (w<<5) + b;
        unsigned bit = 1;
        if (c < 88) {
          int gc = gc0 + c;
          if (rok && (unsigned)gc < (unsigned)IMG) bit = (unsigned)(targ[base+(long)gr*IMG+gc] != 0);
        }
        bits |= bit << b;
      }
      Ta[u] = bits;
    }
  }
  __syncthreads();

  // col validity masks (BND)
  unsigned cm0=~0u, cm1=~0u, cm2=0x00FFFFFFu;
  bool colO = false;
  if (BND) {
    int lo = (-gc0 > 0) ? -gc0 : 0;
    int hi = (IMG - gc0 < 88) ? (IMG - gc0) : 88;
    colO = (lo > 0) || (hi < 88);
    unsigned m[3];
    #pragma unroll
    for (int w=0; w<3; ++w){
      int l = lo - (w<<5); if (l<0) l=0;
      int h = hi - (w<<5); if (h>32) h=32;
      unsigned mm = 0;
      if (h > l) {
        unsigned top = (h>=32)? ~0u : ((1u<<h)-1u);
        unsigned bot = (l<=0)? 0u : ((1u<<l)-1u);
        mm = top & ~bot;
      }
      m[w]=mm;
    }
    cm0=m[0]; cm1=m[1]; cm2=m[2] & 0x00FFFFFF;
  }

  // erode ownership: 18 tall-5 strips x 12 quads = 216 units
  const bool eact0 = (tid < 216);
  const int es = tid / 12, eq = tid - es*12;
  const int s5 = es * 5;                 // first erode px row of strip
  const int ew = eq << 2;                // quad word 0,4,...,44
  // targ erode: word 3+u (rows 1..86 = words 3..260)
  const int to = 3 + tid;
  const int twd = tid - (tid/3)*3;
  const bool tex = (tid < 2);
  const int to2 = 259 + tid;
  const int twd2 = (256+tid) - ((256+tid)/3)*3;

  // interior ownership: 2 rows x 8 px per thread
  const int qc = tid & 7;
  const int rg = tid >> 3;
  const int r0 = HALO + (rg<<1);         // px rows 12..74
  const int wq = 8 + (qc<<2);            // words 8..36 (px 12..75)
  const int bp = 12 + (qc<<3);

  h2 ep[8];
  {
    uint4 a0 = *(const uint4*)&P[(r0+1)*SPP + wq];
    uint4 a1 = *(const uint4*)&P[(r0+2)*SPP + wq];
    ep[0]=u2h(a0.x); ep[1]=u2h(a0.y); ep[2]=u2h(a0.z); ep[3]=u2h(a0.w);
    ep[4]=u2h(a1.x); ep[5]=u2h(a1.y); ep[6]=u2h(a1.z); ep[7]=u2h(a1.w);
    #pragma unroll
    for (int i=0;i<8;++i){ val[i]=ep[i]; skel[i]=(h2)(_Float16)0.0f; }
  }
  {
    int oa = r0*3, ob = (r0+1)*3;
    tbits = extract8(Ta[oa],Ta[oa+1],Ta[oa+2],bp)
          | (extract8(Ta[ob],Ta[ob+1],Ta[ob+2],bp) << 8);
  }
  unsigned tp0=0,tp1=0,tp2=0, sk0=0,sk1=0,sk2=0;
  const bool td = (tid < 64);
  const int tro = (12 + tid)*3;
  if (td) { tp0=Ta[tro]; tp1=Ta[tro+1]; tp2=Ta[tro+2]; }

  const h2 onev  = {(_Float16)1.0f,(_Float16)1.0f};
  const h2 zerov = {(_Float16)0.0f,(_Float16)0.0f};

  for (int j=0;j<11;++j){
    // ---- erode reads + compute (rolling 3-row window, results in regs) ----
    uint4 e[5];
    const bool act = eact0 && (s5+4 >= j+1) && (s5 <= 86-j);
    if (act){
      uint4 rm = *(const uint4*)&P[s5*SPP + ew];         // px row s5-1
      uint4 rc = *(const uint4*)&P[(s5+1)*SPP + ew];     // px row s5
      #pragma unroll
      for (int t=0;t<5;++t){
        int brn = s5 + 2 + t; brn = (brn > 89) ? 89 : brn;
        uint4 rn = *(const uint4*)&P[brn*SPP + ew];
        int brc = s5 + 1 + t; brc = (brc > 89) ? 89 : brc;
        h2 lw = u2h(P[brc*SPP + ew - 1]);
        h2 rv = u2h(P[brc*SPP + ew + 4]);
        e[t] = erode5(rm, rc, rn, lw, rv);
        rm = rc; rc = rn;
      }
    }
    // ---- targ erode (read+compute) ----
    unsigned tres, tres2;
    {
      unsigned own=Ta[to], up=Ta[to-3], dn=Ta[to+3];
      unsigned le = (twd>0)? Ta[to-1] : ~0u;
      unsigned ri = (twd<2)? Ta[to+1] : ~0u;
      unsigned h = own & ((own>>1)|(ri<<31)) & ((own<<1)|(le>>31));
      tres = h & up & dn;
    }
    if (tex){
      unsigned own=Ta[to2], up=Ta[to2-3], dn=Ta[to2+3];
      unsigned le = (twd2>0)? Ta[to2-1] : ~0u;
      unsigned ri = (twd2<2)? Ta[to2+1] : ~0u;
      unsigned h = own & ((own>>1)|(ri<<31)) & ((own<<1)|(le>>31));
      tres2 = h & up & dn;
    }
    __syncthreads();
    // ---- writes ----
    if (act){
      #pragma unroll
      for (int t=0;t<5;++t){
        int br = s5 + 1 + t; br = (br > 89) ? 89 : br;   // row 89 = guard, clobber OK
        *(uint4*)&P[br*SPP + ew] = e[t];
      }
    }
    Ta[to] = tres;
    if (tex) Ta[to2] = tres2;
    __syncthreads();

    if (BND) {  // re-stamp OOB to erode-neutral sentinel
      if (gr0 < 0) {
        for (int i=tid;i<12*44;i+=256){ int r=i/44; P[(1+r)*SPP+2+(i-r*44)] = SEN2; }
        if (tid < 36) Ta[tid] = ~0u;
      }
      if (gr0 + 88 > IMG) {
        for (int i=tid;i<12*44;i+=256){ int r=i/44; P[(77+r)*SPP+2+(i-r*44)] = SEN2; }
        if (tid < 36) Ta[228+tid] = ~0u;
      }
      if (colO) {
        if (gc0 < 0)
          for (int i=tid;i<88*6;i+=256){ int r=i/6; P[(1+r)*SPP+2+(i-r*6)] = SEN2; }
        if (gc0 + 88 > IMG)
          for (int i=tid;i<88*6;i+=256){ int r=i/6; P[(1+r)*SPP+40+(i-r*6)] = SEN2; }
        for (int i=tid;i<264;i+=256){
          int r=i/3, w=i-r*3;
          unsigned nm = (w==0)?~cm0:((w==1)?~cm1:~cm2);
          Ta[i] |= nm;
        }
      }
      __syncthreads();
    }

    // ---- pred 3x3 dilate at own 2x8 px + skel update (reads P = e_j) ----
    h2 H[4][4];
    uint4 cap0, cap1;
    #pragma unroll
    for (int k=0;k<4;++k){
      int ro = (r0+k)*SPP + wq;              // px rows r0-1..r0+2
      uint4 c = *(const uint4*)&P[ro];
      h2 lwv = u2h(P[ro-1]);
      h2 rwv = u2h(P[ro+4]);
      if (k==1) cap0 = c;
      if (k==2) cap1 = c;
      h2 a0=u2h(c.x),a1=u2h(c.y),a2=u2h(c.z),a3=u2h(c.w);
      if (BND){
        a0=unsent(a0,onev,zerov); a1=unsent(a1,onev,zerov);
        a2=unsent(a2,onev,zerov); a3=unsent(a3,onev,zerov);
        lwv=unsent(lwv,onev,zerov); rwv=unsent(rwv,onev,zerov);
      }
      h2 f0=funnel(a0,lwv), f1=funnel(a1,a0), f2=funnel(a2,a1), f3=funnel(a3,a2), f4=funnel(rwv,a3);
      H[k][0]=pmax(pmax(f0,f1),a0);
      H[k][1]=pmax(pmax(f1,f2),a1);
      H[k][2]=pmax(pmax(f2,f3),a2);
      H[k][3]=pmax(pmax(f3,f4),a3);
    }
    #pragma unroll
    for (int i=0;i<4;++i){
      h2 m0 = pmax(pmax(H[0][i],H[1][i]),H[2][i]);
      h2 m1 = pmax(pmax(H[1][i],H[2][i]),H[3][i]);
      h2 d0 = pmax(ep[i]-m0, zerov);
      h2 d1 = pmax(ep[4+i]-m1, zerov);
      h2 x0 = d0 - skel[i]*d0;
      h2 x1 = d1 - skel[4+i]*d1;
      skel[i]   = skel[i]   + pmax(x0, zerov);
      skel[4+i] = skel[4+i] + pmax(x1, zerov);
    }
    ep[0]=u2h(cap0.x); ep[1]=u2h(cap0.y); ep[2]=u2h(cap0.z); ep[3]=u2h(cap0.w);
    ep[4]=u2h(cap1.x); ep[5]=u2h(cap1.y); ep[6]=u2h(cap1.z); ep[7]=u2h(cap1.w);

    // ---- targ dilate + skel_t ----
    if (td) {
      unsigned o0=Ta[tro], o1=Ta[tro+1], o2=Ta[tro+2];
      unsigned u0=Ta[tro-3], u1=Ta[tro-2], u2=Ta[tro-1];
      unsigned n0=Ta[tro+3], n1=Ta[tro+4], n2=Ta[tro+5];
      unsigned v0,v1,v2;
      if (BND){
        unsigned mu = ((unsigned)(gr0 + 11 + tid) < (unsigned)IMG) ? ~0u : 0u;
        unsigned md = ((unsigned)(gr0 + 13 + tid) < (unsigned)IMG) ? ~0u : 0u;
        v0 = ((u0&mu)|o0|(n0&md)) & cm0;
        v1 = ((u1&mu)|o1|(n1&md)) & cm1;
        v2 = ((u2&mu)|o2|(n2&md)) & cm2;
      } else {
        v0 = u0|o0|n0; v1 = u1|o1|n1; v2 = u2|o2|n2;
      }
      unsigned d0 = v0 | (v0<<1) | (v0>>1) | (v1<<31);
      unsigned d1 = v1 | (v1<<1) | (v0>>31) | (v1>>1) | (v2<<31);
      unsigned d2 = v2 | (v2<<1) | (v1>>31) | (v2>>1);
      sk0 |= tp0 & ~d0;
      sk1 |= tp1 & ~d1;
      sk2 |= tp2 & ~d2;
      tp0 = o0; tp1 = o1; tp2 = o2;
    }
  }

  __syncthreads();
  if (td){ Ta[3*tid]=sk0; Ta[3*tid+1]=sk1; Ta[3*tid+2]=sk2; }
  __syncthreads();
  {
    int o = (r0-12)*3;
    skbits = extract8(Ta[o],Ta[o+1],Ta[o+2],bp)
           | (extract8(Ta[o+3],Ta[o+4],Ta[o+5],bp) << 8);
  }
}

__global__ __launch_bounds__(256,4)
void cl_dice_main(const float* __restrict__ pred, const int* __restrict__ targ,
                  float* __restrict__ ws) {
  __shared__ alignas(16) unsigned sP[NPRED];
  __shared__ unsigned sTA[264];
  const int tid = threadIdx.x;
  const int gr0 = blockIdx.y * TILE - HALO;
  const int gc0 = blockIdx.x * TILE - HALO;
  const long base = (long)blockIdx.z * (long)(IMG * IMG);

  h2 val[8], skel[8]; unsigned tbits, skbits;
  const bool bnd = (blockIdx.x == 0) | (blockIdx.x == gridDim.x - 1) |
                   (blockIdx.y == 0) | (blockIdx.y == gridDim.y - 1);
  if (!bnd) pipeline<false>(pred, targ, base, gr0, gc0, tid, sP, sTA, val, skel, tbits, skbits);
  else      pipeline<true >(pred, targ, base, gr0, gc0, tid, sP, sTA, val, skel, tbits, skbits);

  float s[7] = {0,0,0,0,0,0,0};
  #pragma unroll
  for (int k=0;k<8;++k){
    int bb = ((k>>2)<<3) + ((k&3)<<1);
    float p0=(float)val[k].x,  p1=(float)val[k].y;
    float a0=(float)skel[k].x, a1=(float)skel[k].y;
    float t0=(float)((tbits>>bb)&1u),  t1=(float)((tbits>>(bb+1))&1u);
    float b0=(float)((skbits>>bb)&1u), b1=(float)((skbits>>(bb+1))&1u);
    s[0]+=a0+a1;        s[1]+=a0*t0+a1*t1;
    s[2]+=b0+b1;        s[3]+=b0*p0+b1*p1;
    s[4]+=p0*t0+p1*t1;  s[5]+=p0+p1;  s[6]+=t0+t1;
  }

  float* red = (float*)sP;
  #pragma unroll
  for (int k=0;k<7;++k){
    float v = s[k];
    v += __shfl_down(v,32); v += __shfl_down(v,16); v += __shfl_down(v,8);
    v += __shfl_down(v,4);  v += __shfl_down(v,2);  v += __shfl_down(v,1);
    if ((tid & 63) == 0) red[(tid>>6)*8 + k] = v;
  }
  __syncthreads();
  if (tid < 7) {
    float v = red[tid] + red[8+tid] + red[16+tid] + red[24+tid];
    int blk = (blockIdx.z * gridDim.y + blockIdx.y) * gridDim.x + blockIdx.x;
    ws[blk*8 + tid] = v;
  }
}

__global__ __launch_bounds__(256)
void cl_dice_finalize(const float* __restrict__ ws, float* __restrict__ out, int nblk) {
  __shared__ float red[4][8];
  int tid = threadIdx.x;
  float acc[7] = {0,0,0,0,0,0,0};
  for (int i=tid; i<nblk; i+=256) {
    #pragma unroll
    for (int k=0;k<7;++k) acc[k] += ws[i*8 + k];
  }
  #pragma unroll
  for (int k=0;k<7;++k){
    float v = acc[k];
    v += __shfl_down(v,32); v += __shfl_down(v,16); v += __shfl_down(v,8);
    v += __shfl_down(v,4);  v += __shfl_down(v,2);  v += __shfl_down(v,1);
    if ((tid & 63) == 0) red[tid>>6][k] = v;
  }
  __syncthreads();
  if (tid == 0) {
    float t0[7];
    #pragma unroll
    for (int k=0;k<7;++k) t0[k] = red[0][k] + red[1][k] + red[2][k] + red[3][k];
    float sum_sp = t0[0], sum_spt = t0[1], sum_st = t0[2], sum_stp = t0[3];
    float inter  = t0[4], sum_p   = t0[5], sum_t  = t0[6];
    float tprec = (sum_spt + 1.0f) / (sum_sp + 1.0f);
    float tsens = (sum_stp + 1.0f) / (sum_st + 1.0f);
    float cl    = 2.0f * tprec * tsens / (tprec + tsens + 1e-7f);
    float dice  = (2.0f * inter + 1.0f) / (sum_p + sum_t + 1.0f);
    out[0] = 1.0f - 0.5f * (dice + cl);
  }
}

extern "C" void kernel_launch(void* const* d_in, const int* in_sizes, int n_in,
                              void* d_out, int out_size, void* d_ws, size_t ws_size,
                              hipStream_t stream) {
  const float* pred = (const float*)d_in[0];
  const int*   targ = (const int*)d_in[1];
  float* ws  = (float*)d_ws;
  float* out = (float*)d_out;

  const int B = in_sizes[0] / (IMG * IMG);     // 8
  dim3 grid(IMG / TILE, IMG / TILE, B);        // 16 x 16 x 8 = 2048 blocks
  cl_dice_main<<<grid, 256, 0, stream>>>(pred, targ, ws);

  const int nblk = (IMG / TILE) * (IMG / TILE) * B;
  cl_dice_finalize<<<1, 256, 0, stream>>>(ws, out, nblk);
}

// Round 12
// 243.696 us; speedup vs baseline: 1.3184x; 1.0164x over previous
//
#include <hip/hip_runtime.h>
#include <math.h>

#define IMG  1024
#define TILE 64
#define HALO 12
#define SPP  52              // words/row: 2 pad + 44 data (words 2..45) + 6 pad (46..51)
#define NPRED (90*SPP)       // buffer rows 0..89 = px rows -1..88 (guard top/bottom)
#define SEN2 0x40004000u     // (2.0h,2.0h) sentinel = +inf (all real values <= 1)

// pred: fp16 pair-packed 2 px/word, DOUBLE-buffered (1 barrier/step).
// targ: binary bit-packed 32 px/word, double-buffered.
typedef _Float16 h2 __attribute__((ext_vector_type(2)));
union UH { unsigned u; h2 h; };
__device__ __forceinline__ h2 u2h(unsigned u){ UH x; x.u=u; return x.h; }
__device__ __forceinline__ unsigned h2u(h2 h){ UH x; x.h=h; return x.u; }
__device__ __forceinline__ h2 pmin(h2 a, h2 b){ return __builtin_elementwise_min(a,b); }
__device__ __forceinline__ h2 pmax(h2 a, h2 b){ return __builtin_elementwise_max(a,b); }
__device__ __forceinline__ h2 funnel(h2 hi_src, h2 lo_src){
  return u2h((h2u(lo_src)>>16) | (h2u(hi_src)<<16));
}
__device__ __forceinline__ float sigmoidf(float x){ return 1.0f/(1.0f+__expf(-x)); }
__device__ __forceinline__ h2 unsent(h2 x, h2 onev, h2 zerov){
  h2 t = pmax(x-onev, zerov); return x - t - t;   // 2.0 -> 0, identity on [0,1]
}
__device__ __forceinline__ unsigned extract8(unsigned w0, unsigned w1, unsigned w2, int bp){
  unsigned long long lo = (unsigned long long)w0 | ((unsigned long long)w1<<32);
  unsigned long long hi = (unsigned long long)w1 | ((unsigned long long)w2<<32);
  unsigned a = (unsigned)(lo >> bp);
  unsigned b = (unsigned)(hi >> (bp & 31));
  return ((bp < 32) ? a : b) & 0xFFu;
}
// 5-pt cross erode of one 8-px quad row: center rm/rc/rn, left/right edge words
__device__ __forceinline__ uint4 erode5(uint4 rm, uint4 rc, uint4 rn, h2 lw, h2 rv){
  h2 a0=u2h(rc.x), a1=u2h(rc.y), a2=u2h(rc.z), a3=u2h(rc.w);
  h2 v0=pmin(u2h(rm.x), u2h(rn.x));
  h2 v1=pmin(u2h(rm.y), u2h(rn.y));
  h2 v2=pmin(u2h(rm.z), u2h(rn.z));
  h2 v3=pmin(u2h(rm.w), u2h(rn.w));
  h2 f0=funnel(a0,lw), f1=funnel(a1,a0), f2=funnel(a2,a1), f3=funnel(a3,a2), f4=funnel(rv,a3);
  uint4 e;
  e.x=h2u(pmin(pmin(f0,f1),pmin(v0,a0)));
  e.y=h2u(pmin(pmin(f1,f2),pmin(v1,a1)));
  e.z=h2u(pmin(pmin(f2,f3),pmin(v2,a2)));
  e.w=h2u(pmin(pmin(f3,f4),pmin(v3,a3)));
  return e;
}

template<bool BND>
__device__ void pipeline(const float* __restrict__ pred, const int* __restrict__ targ,
                         long base, int gr0, int gc0, int tid,
                         unsigned* A, unsigned* B, unsigned* Ta, unsigned* Tb,
                         h2 val[8], h2 skel[8], unsigned &tbits, unsigned &skbits) {
  // ---- stamp guard rows (px -1, 88) and pad cols for BOTH buffers ----
  for (int i = tid; i < 104; i += 256) {
    int r = (i < 52) ? 0 : 89, c = (i < 52) ? i : i - 52;
    A[r*SPP + c] = SEN2;  B[r*SPP + c] = SEN2;
  }
  for (int i = tid; i < 704; i += 256) {
    int r = 1 + (i >> 3), w = i & 7;
    w = (w < 2) ? w : 44 + w;
    A[r*SPP + w] = SEN2;  B[r*SPP + w] = SEN2;
  }
  // ---- global -> LDS ----
  if (!BND) {
    #pragma unroll
    for (int k=0;k<4;++k){
      int u = tid + (k<<8);
      if (u < 968){                          // 88 rows x 11 groups of 8 px
        int r = u/11, q = u - r*11;
        long g = base + (long)(gr0+r)*IMG + gc0 + (q<<3);
        float4 pa = *(const float4*)(pred+g);
        float4 pb = *(const float4*)(pred+g+4);
        h2 w0 = {(_Float16)sigmoidf(pa.x), (_Float16)sigmoidf(pa.y)};
        h2 w1 = {(_Float16)sigmoidf(pa.z), (_Float16)sigmoidf(pa.w)};
        h2 w2 = {(_Float16)sigmoidf(pb.x), (_Float16)sigmoidf(pb.y)};
        h2 w3 = {(_Float16)sigmoidf(pb.z), (_Float16)sigmoidf(pb.w)};
        int o = (1+r)*SPP + 2 + (q<<2);
        uint2 d0; d0.x=h2u(w0); d0.y=h2u(w1);
        uint2 d1; d1.x=h2u(w2); d1.y=h2u(w3);
        *(uint2*)&A[o]   = d0;
        *(uint2*)&A[o+2] = d1;
      }
    }
    #pragma unroll
    for (int k=0;k<2;++k){
      int u = tid + (k<<8);
      if (u < 264){                          // 88 rows x 3 bit-words
        int r = u/3, w = u - r*3;
        long g = base + (long)(gr0+r)*IMG + gc0 + (w<<5);
        unsigned bits = 0;
        #pragma unroll
        for (int i=0;i<8;++i){
          if (w < 2 || i < 6) {
            int4 tv = *(const int4*)(targ + g + (i<<2));
            unsigned nib = (unsigned)(tv.x!=0) | ((unsigned)(tv.y!=0)<<1)
                         | ((unsigned)(tv.z!=0)<<2) | ((unsigned)(tv.w!=0)<<3);
            bits |= nib << (i<<2);
          }
        }
        if (w==2) bits |= 0xFF000000u;       // pseudo px 88..95: erode-neutral 1
        Ta[u] = bits;
      }
    }
  } else {
    for (int i=tid; i<88*44; i+=256){
      int r = i/44, wd = i - r*44;
      int gr = gr0 + r;
      bool rok = (unsigned)gr < (unsigned)IMG;
      int gca = gc0 + (wd<<1), gcb = gca + 1;
      _Float16 va = (_Float16)2.0f, vb = (_Float16)2.0f;
      if (rok && (unsigned)gca < (unsigned)IMG) va = (_Float16)sigmoidf(pred[base + (long)gr*IMG + gca]);
      if (rok && (unsigned)gcb < (unsigned)IMG) vb = (_Float16)sigmoidf(pred[base + (long)gr*IMG + gcb]);
      h2 w; w.x = va; w.y = vb;
      A[(1+r)*SPP + 2 + wd] = h2u(w);
    }
    for (int u=tid; u<264; u+=256){
      int r = u/3, w = u - r*3;
      int gr = gr0 + r;
      bool rok = (unsigned)gr < (unsigned)IMG;
      unsigned bits = 0;
      for (int b=0;b<32;++b){
        int c = (w<<5) + b;
        unsigned bit = 1;
        if (c < 88) {
          int gc = gc0 + c;
          if (rok && (unsigned)gc < (unsigned)IMG) bit = (unsigned)(targ[base+(long)gr*IMG+gc] != 0);
        }
        bits |= bit << b;
      }
      Ta[u] = bits;
    }
  }
  __syncthreads();

  // col validity masks (BND)
  unsigned cm0=~0u, cm1=~0u, cm2=0x00FFFFFFu;
  bool colO = false;
  if (BND) {
    int lo = (-gc0 > 0) ? -gc0 : 0;
    int hi = (IMG - gc0 < 88) ? (IMG - gc0) : 88;
    colO = (lo > 0) || (hi < 88);
    unsigned m[3];
    #pragma unroll
    for (int w=0; w<3; ++w){
      int l = lo - (w<<5); if (l<0) l=0;
      int h = hi - (w<<5); if (h>32) h=32;
      unsigned mm = 0;
      if (h > l) {
        unsigned top = (h>=32)? ~0u : ((1u<<h)-1u);
        unsigned bot = (l<=0)? 0u : ((1u<<l)-1u);
        mm = top & ~bot;
      }
      m[w]=mm;
    }
    cm0=m[0]; cm1=m[1]; cm2=m[2] & 0x00FFFFFF;
  }

  // erode ownership: 18 tall-5 strips x 12 quads = 216 units
  const bool eact0 = (tid < 216);
  const int es = tid / 12, eq = tid - es*12;
  const int s5 = es * 5;                 // first erode px row of strip
  const int ew = eq << 2;                // quad word 0,4,...,44
  const int c_lo = (eq<<3) + 3;          // quad px col hi+? : 8q+3
  const int c_hi = (eq<<3) - 4;          // 8q-4
  // targ erode: word 3+u (rows 1..86 = words 3..260)
  const int to = 3 + tid;
  const int twd = tid - (tid/3)*3;
  const bool tex = (tid < 2);
  const int to2 = 259 + tid;
  const int twd2 = (256+tid) - ((256+tid)/3)*3;

  // interior ownership: 2 rows x 8 px per thread
  const int qc = tid & 7;
  const int rg = tid >> 3;
  const int r0 = HALO + (rg<<1);         // px rows 12..74
  const int wq = 8 + (qc<<2);            // words 8..36 (px 12..75)
  const int bp = 12 + (qc<<3);

  h2 ep[8];
  {
    uint4 a0 = *(const uint4*)&A[(r0+1)*SPP + wq];
    uint4 a1 = *(const uint4*)&A[(r0+2)*SPP + wq];
    ep[0]=u2h(a0.x); ep[1]=u2h(a0.y); ep[2]=u2h(a0.z); ep[3]=u2h(a0.w);
    ep[4]=u2h(a1.x); ep[5]=u2h(a1.y); ep[6]=u2h(a1.z); ep[7]=u2h(a1.w);
    #pragma unroll
    for (int i=0;i<8;++i){ val[i]=ep[i]; skel[i]=(h2)(_Float16)0.0f; }
  }
  {
    int oa = r0*3, ob = (r0+1)*3;
    tbits = extract8(Ta[oa],Ta[oa+1],Ta[oa+2],bp)
          | (extract8(Ta[ob],Ta[ob+1],Ta[ob+2],bp) << 8);
  }
  unsigned tp0=0,tp1=0,tp2=0, sk0=0,sk1=0,sk2=0;
  const bool td = (tid < 64);
  const int tro = (12 + tid)*3;
  if (td) { tp0=Ta[tro]; tp1=Ta[tro+1]; tp2=Ta[tro+2]; }

  const h2 onev  = {(_Float16)1.0f,(_Float16)1.0f};
  const h2 zerov = {(_Float16)0.0f,(_Float16)0.0f};

  for (int j=0;j<11;++j){
    // ---- erode A -> B (rolling 3-row window, immediate writes) ----
    const bool act = eact0 && (s5+4 >= j+1) && (s5 <= 86-j)
                           && (c_lo >= j+1) && (c_hi <= 86-j);
    if (act){
      uint4 rm = *(const uint4*)&A[s5*SPP + ew];         // px row s5-1
      uint4 rc = *(const uint4*)&A[(s5+1)*SPP + ew];     // px row s5
      #pragma unroll
      for (int t=0;t<5;++t){
        int brn = s5 + 2 + t; brn = (brn > 89) ? 89 : brn;
        uint4 rn = *(const uint4*)&A[brn*SPP + ew];
        int brc = s5 + 1 + t; brc = (brc > 89) ? 89 : brc;
        h2 lw = u2h(A[brc*SPP + ew - 1]);
        h2 rv = u2h(A[brc*SPP + ew + 4]);
        *(uint4*)&B[brc*SPP + ew] = erode5(rm, rc, rn, lw, rv);
        rm = rc; rc = rn;
      }
    }
    // ---- targ erode Ta -> Tb ----
    {
      unsigned own=Ta[to], up=Ta[to-3], dn=Ta[to+3];
      unsigned le = (twd>0)? Ta[to-1] : ~0u;
      unsigned ri = (twd<2)? Ta[to+1] : ~0u;
      unsigned h = own & ((own>>1)|(ri<<31)) & ((own<<1)|(le>>31));
      Tb[to] = h & up & dn;
    }
    if (tex){
      unsigned own=Ta[to2], up=Ta[to2-3], dn=Ta[to2+3];
      unsigned le = (twd2>0)? Ta[to2-1] : ~0u;
      unsigned ri = (twd2<2)? Ta[to2+1] : ~0u;
      unsigned h = own & ((own>>1)|(ri<<31)) & ((own<<1)|(le>>31));
      Tb[to2] = h & up & dn;
    }
    __syncthreads();

    if (BND) {  // re-stamp OOB to erode-neutral sentinel (on B / Tb)
      if (gr0 < 0) {
        for (int i=tid;i<12*44;i+=256){ int r=i/44; B[(1+r)*SPP+2+(i-r*44)] = SEN2; }
        if (tid < 36) Tb[tid] = ~0u;
      }
      if (gr0 + 88 > IMG) {
        for (int i=tid;i<12*44;i+=256){ int r=i/44; B[(77+r)*SPP+2+(i-r*44)] = SEN2; }
        if (tid < 36) Tb[228+tid] = ~0u;
      }
      if (colO) {
        if (gc0 < 0)
          for (int i=tid;i<88*6;i+=256){ int r=i/6; B[(1+r)*SPP+2+(i-r*6)] = SEN2; }
        if (gc0 + 88 > IMG)
          for (int i=tid;i<88*6;i+=256){ int r=i/6; B[(1+r)*SPP+40+(i-r*6)] = SEN2; }
        for (int i=tid;i<264;i+=256){
          int r=i/3, w=i-r*3;
          unsigned nm = (w==0)?~cm0:((w==1)?~cm1:~cm2);
          Tb[i] |= nm;
        }
      }
      __syncthreads();
    }

    // ---- pred 3x3 dilate of B at own 2x8 px + skel update (reads B only) ----
    h2 H[4][4];
    uint4 cap0, cap1;
    #pragma unroll
    for (int k=0;k<4;++k){
      int ro = (r0+k)*SPP + wq;              // px rows r0-1..r0+2
      uint4 c = *(const uint4*)&B[ro];
      h2 lwv = u2h(B[ro-1]);
      h2 rwv = u2h(B[ro+4]);
      if (k==1) cap0 = c;
      if (k==2) cap1 = c;
      h2 a0=u2h(c.x),a1=u2h(c.y),a2=u2h(c.z),a3=u2h(c.w);
      if (BND){
        a0=unsent(a0,onev,zerov); a1=unsent(a1,onev,zerov);
        a2=unsent(a2,onev,zerov); a3=unsent(a3,onev,zerov);
        lwv=unsent(lwv,onev,zerov); rwv=unsent(rwv,onev,zerov);
      }
      h2 f0=funnel(a0,lwv), f1=funnel(a1,a0), f2=funnel(a2,a1), f3=funnel(a3,a2), f4=funnel(rwv,a3);
      H[k][0]=pmax(pmax(f0,f1),a0);
      H[k][1]=pmax(pmax(f1,f2),a1);
      H[k][2]=pmax(pmax(f2,f3),a2);
      H[k][3]=pmax(pmax(f3,f4),a3);
    }
    #pragma unroll
    for (int i=0;i<4;++i){
      h2 m0 = pmax(pmax(H[0][i],H[1][i]),H[2][i]);
      h2 m1 = pmax(pmax(H[1][i],H[2][i]),H[3][i]);
      h2 d0 = pmax(ep[i]-m0, zerov);
      h2 d1 = pmax(ep[4+i]-m1, zerov);
      h2 x0 = d0 - skel[i]*d0;
      h2 x1 = d1 - skel[4+i]*d1;
      skel[i]   = skel[i]   + pmax(x0, zerov);
      skel[4+i] = skel[4+i] + pmax(x1, zerov);
    }
    ep[0]=u2h(cap0.x); ep[1]=u2h(cap0.y); ep[2]=u2h(cap0.z); ep[3]=u2h(cap0.w);
    ep[4]=u2h(cap1.x); ep[5]=u2h(cap1.y); ep[6]=u2h(cap1.z); ep[7]=u2h(cap1.w);

    // ---- targ dilate + skel_t (reads Tb only) ----
    if (td) {
      unsigned o0=Tb[tro], o1=Tb[tro+1], o2=Tb[tro+2];
      unsigned u0=Tb[tro-3], u1=Tb[tro-2], u2=Tb[tro-1];
      unsigned n0=Tb[tro+3], n1=Tb[tro+4], n2=Tb[tro+5];
      unsigned v0,v1,v2;
      if (BND){
        unsigned mu = ((unsigned)(gr0 + 11 + tid) < (unsigned)IMG) ? ~0u : 0u;
        unsigned md = ((unsigned)(gr0 + 13 + tid) < (unsigned)IMG) ? ~0u : 0u;
        v0 = ((u0&mu)|o0|(n0&md)) & cm0;
        v1 = ((u1&mu)|o1|(n1&md)) & cm1;
        v2 = ((u2&mu)|o2|(n2&md)) & cm2;
      } else {
        v0 = u0|o0|n0; v1 = u1|o1|n1; v2 = u2|o2|n2;
      }
      unsigned d0 = v0 | (v0<<1) | (v0>>1) | (v1<<31);
      unsigned d1 = v1 | (v1<<1) | (v0>>31) | (v1>>1) | (v2<<31);
      unsigned d2 = v2 | (v2<<1) | (v1>>31) | (v2>>1);
      sk0 |= tp0 & ~d0;
      sk1 |= tp1 & ~d1;
      sk2 |= tp2 & ~d2;
      tp0 = o0; tp1 = o1; tp2 = o2;
    }
    // swap buffers; no trailing barrier needed: next erode reads B (all
    // writers passed the barrier) and writes old A (read only pre-barrier).
    unsigned* t1 = A;  A = B;  B = t1;
    unsigned* t2 = Ta; Ta = Tb; Tb = t2;
  }

  __syncthreads();
  if (td){ Ta[3*tid]=sk0; Ta[3*tid+1]=sk1; Ta[3*tid+2]=sk2; }
  __syncthreads();
  {
    int o = (r0-12)*3;
    skbits = extract8(Ta[o],Ta[o+1],Ta[o+2],bp)
           | (extract8(Ta[o+3],Ta[o+4],Ta[o+5],bp) << 8);
  }
}

__global__ __launch_bounds__(256,4)
void cl_dice_main(const float* __restrict__ pred, const int* __restrict__ targ,
                  float* __restrict__ ws) {
  __shared__ alignas(16) unsigned sPA[NPRED];
  __shared__ alignas(16) unsigned sPB[NPRED];
  __shared__ unsigned sTA[264], sTB[264];
  const int tid = threadIdx.x;
  const int gr0 = blockIdx.y * TILE - HALO;
  const int gc0 = blockIdx.x * TILE - HALO;
  const long base = (long)blockIdx.z * (long)(IMG * IMG);

  h2 val[8], skel[8]; unsigned tbits, skbits;
  const bool bnd = (blockIdx.x == 0) | (blockIdx.x == gridDim.x - 1) |
                   (blockIdx.y == 0) | (blockIdx.y == gridDim.y - 1);
  if (!bnd) pipeline<false>(pred, targ, base, gr0, gc0, tid, sPA, sPB, sTA, sTB, val, skel, tbits, skbits);
  else      pipeline<true >(pred, targ, base, gr0, gc0, tid, sPA, sPB, sTA, sTB, val, skel, tbits, skbits);

  float s[7] = {0,0,0,0,0,0,0};
  #pragma unroll
  for (int k=0;k<8;++k){
    int bb = ((k>>2)<<3) + ((k&3)<<1);
    float p0=(float)val[k].x,  p1=(float)val[k].y;
    float a0=(float)skel[k].x, a1=(float)skel[k].y;
    float t0=(float)((tbits>>bb)&1u),  t1=(float)((tbits>>(bb+1))&1u);
    float b0=(float)((skbits>>bb)&1u), b1=(float)((skbits>>(bb+1))&1u);
    s[0]+=a0+a1;        s[1]+=a0*t0+a1*t1;
    s[2]+=b0+b1;        s[3]+=b0*p0+b1*p1;
    s[4]+=p0*t0+p1*t1;  s[5]+=p0+p1;  s[6]+=t0+t1;
  }

  float* red = (float*)sPA;
  #pragma unroll
  for (int k=0;k<7;++k){
    float v = s[k];
    v += __shfl_down(v,32); v += __shfl_down(v,16); v += __shfl_down(v,8);
    v += __shfl_down(v,4);  v += __shfl_down(v,2);  v += __shfl_down(v,1);
    if ((tid & 63) == 0) red[(tid>>6)*8 + k] = v;
  }
  __syncthreads();
  if (tid < 7) {
    float v = red[tid] + red[8+tid] + red[16+tid] + red[24+tid];
    int blk = (blockIdx.z * gridDim.y + blockIdx.y) * gridDim.x + blockIdx.x;
    ws[blk*8 + tid] = v;
  }
}

__global__ __launch_bounds__(256)
void cl_dice_finalize(const float* __restrict__ ws, float* __restrict__ out, int nblk) {
  __shared__ float red[4][8];
  int tid = threadIdx.x;
  float acc[7] = {0,0,0,0,0,0,0};
  for (int i=tid; i<nblk; i+=256) {
    #pragma unroll
    for (int k=0;k<7;++k) acc[k] += ws[i*8 + k];
  }
  #pragma unroll
  for (int k=0;k<7;++k){
    float v = acc[k];
    v += __shfl_down(v,32); v += __shfl_down(v,16); v += __shfl_down(v,8);
    v += __shfl_down(v,4);  v += __shfl_down(v,2);  v += __shfl_down(v,1);
    if ((tid & 63) == 0) red[tid>>6][k] = v;
  }
  __syncthreads();
  if (tid == 0) {
    float t0[7];
    #pragma unroll
    for (int k=0;k<7;++k) t0[k] = red[0][k] + red[1][k] + red[2][k] + red[3][k];
    float sum_sp = t0[0], sum_spt = t0[1], sum_st = t0[2], sum_stp = t0[3];
    float inter  = t0[4], sum_p   = t0[5], sum_t  = t0[6];
    float tprec = (sum_spt + 1.0f) / (sum_sp + 1.0f);
    float tsens = (sum_stp + 1.0f) / (sum_st + 1.0f);
    float cl    = 2.0f * tprec * tsens / (tprec + tsens + 1e-7f);
    float dice  = (2.0f * inter + 1.0f) / (sum_p + sum_t + 1.0f);
    out[0] = 1.0f - 0.5f * (dice + cl);
  }
}

extern "C" void kernel_launch(void* const* d_in, const int* in_sizes, int n_in,
                              void* d_out, int out_size, void* d_ws, size_t ws_size,
                              hipStream_t stream) {
  const float* pred = (const float*)d_in[0];
  const int*   targ = (const int*)d_in[1];
  float* ws  = (float*)d_ws;
  float* out = (float*)d_out;

  const int B = in_sizes[0] / (IMG * IMG);     // 8
  dim3 grid(IMG / TILE, IMG / TILE, B);        // 16 x 16 x 8 = 2048 blocks
  cl_dice_main<<<grid, 256, 0, stream>>>(pred, targ, ws);

  const int nblk = (IMG / TILE) * (IMG / TILE) * B;
  cl_dice_finalize<<<1, 256, 0, stream>>>(ws, out, nblk);
}